// Round 8
// baseline (92.854 us; speedup 1.0000x reference)
//
#include <hip/hip_runtime.h>

#define LOG2E   1.4426950408889634f

typedef _Float16 fh2 __attribute__((ext_vector_type(2)));   // fdot2 operand type
typedef __fp16   ph2 __attribute__((ext_vector_type(2)));   // cvt_pkrtz result type
typedef float    f32x2 __attribute__((ext_vector_type(2))); // v_pk_*_f32 operand
union h2u { fh2 f; ph2 p; unsigned int u; };
__device__ __forceinline__ unsigned int pk2bits(ph2 h) { h2u t; t.p = h; return t.u; }
__device__ __forceinline__ fh2 pk2f(ph2 h) { h2u t; t.p = h; return t.f; }
__device__ __forceinline__ fh2 bits2f(unsigned int u) { h2u t; t.u = u; return t.f; }

// ---------------- Kernel 1: fused projections (e^proj) + V fp16 pack -------
// 256 threads. blocks 0..127: qc rows (Eq = e^{q@Wq}, fp32). blocks 128..639:
// kct fp32 layout [b][c][h>>2][kv][h&3] holding Ek = e^{k@Wk}; K-blocks with
// all rows >= valid_len exit early (attn reads those rows only as benign
// poison in partially-masked chunks; those scores are masked to -1e6).
// blocks 640..1151: pack V into fp16 kv-pairs: vh[b][p][c] = half2
// {V[b][2p][c], V[b][2p+1][c]} for the dot2-based PV.
// Half-exponent trick: attn computes sig = 1/((Eq*Ek)^2 + 1); stored
// exponents have sigma~16.3 -> overflow needs 7.7 sigma (never), and product
// over/underflow saturates to the CORRECT sigmoid limit (rcp(inf)=0,
// rcp(0+1)=1). No clamping needed. (bf16 kct regressed: halves MLP and adds
// unpack to the dependent path -- R7. fp32 kct is the validated form.)
__global__ __launch_bounds__(256) void proj_kernel(
    const float* __restrict__ q_in, const float* __restrict__ k_in,
    const float* __restrict__ v_in,
    const float* __restrict__ Wq, const float* __restrict__ Wk,
    const int* __restrict__ valid_lens,
    float* __restrict__ qc, float* __restrict__ kct,
    unsigned int* __restrict__ vh)
{
    __shared__ __align__(16) float x_s[8][128];     // 4 KB
    __shared__ __align__(16) float ps[4][8][128];   // 16 KB
    int tid = threadIdx.x;
    int blk = blockIdx.x;

    if (blk >= 640) {                   // ---- V fp16 pair-pack branch ----
        int vb = blk - 640;             // 0..511
        int P  = vb*4 + (tid >> 6);     // global pair 0..2047
        int bb = P >> 9, p = P & 511;
        int lane = tid & 63;
        const float4* r0 = (const float4*)(v_in + ((size_t)(bb*1024 + 2*p))*256) + lane;
        float4 x0 = r0[0];
        float4 x1 = r0[64];             // next kv row (+256 floats)
        uint4 h;
        h.x = pk2bits(__builtin_amdgcn_cvt_pkrtz(x0.x, x1.x));
        h.y = pk2bits(__builtin_amdgcn_cvt_pkrtz(x0.y, x1.y));
        h.z = pk2bits(__builtin_amdgcn_cvt_pkrtz(x0.z, x1.z));
        h.w = pk2bits(__builtin_amdgcn_cvt_pkrtz(x0.w, x1.w));
        ((uint4*)vh)[(size_t)P*64 + lane] = h;
        return;
    }

    bool is_q = (blk < 128);
    int r0 = (is_q ? blk : blk - 128) * 8;
    int bb = r0 >> 10;
    if (!is_q) {
        int vl = valid_lens[bb];
        if ((r0 & 1023) >= vl) return;  // block-uniform: whole block exits
    }
    const float* X = (is_q ? q_in : k_in) + (size_t)r0 * 128;
    const float* W = is_q ? Wq : Wk;

    *(float4*)&x_s[tid >> 5][(tid & 31) * 4] = ((const float4*)X)[tid];
    __syncthreads();

    int hl = tid & 63;                  // column pair {hl, hl+64}
    int dq = tid >> 6;                  // d-quarter (wave-uniform)
    float a0[8] = {0,0,0,0,0,0,0,0};
    float a1[8] = {0,0,0,0,0,0,0,0};
#pragma unroll
    for (int i4 = 0; i4 < 8; ++i4) {
        int d = dq*32 + i4*4;
        float w00 = W[(d+0)*128 + hl], w01 = W[(d+0)*128 + hl + 64];
        float w10 = W[(d+1)*128 + hl], w11 = W[(d+1)*128 + hl + 64];
        float w20 = W[(d+2)*128 + hl], w21 = W[(d+2)*128 + hl + 64];
        float w30 = W[(d+3)*128 + hl], w31 = W[(d+3)*128 + hl + 64];
#pragma unroll
        for (int r = 0; r < 8; ++r) {
            float4 xv = *(const float4*)&x_s[r][d];   // wave-uniform broadcast
            a0[r] = fmaf(xv.x,w00, fmaf(xv.y,w10, fmaf(xv.z,w20, fmaf(xv.w,w30, a0[r]))));
            a1[r] = fmaf(xv.x,w01, fmaf(xv.y,w11, fmaf(xv.z,w21, fmaf(xv.w,w31, a1[r]))));
        }
    }
#pragma unroll
    for (int r = 0; r < 8; ++r) {
        ps[dq][r][hl]      = a0[r];
        ps[dq][r][hl + 64] = a1[r];
    }
    __syncthreads();

    int r  = tid >> 5;
    int c4 = (tid & 31) * 4;
    float4 s0 = *(const float4*)&ps[0][r][c4];
    float4 s1 = *(const float4*)&ps[1][r][c4];
    float4 s2 = *(const float4*)&ps[2][r][c4];
    float4 s3 = *(const float4*)&ps[3][r][c4];
    float4 v;
    v.x = __builtin_amdgcn_exp2f(((s0.x+s1.x)+(s2.x+s3.x))*LOG2E);
    v.y = __builtin_amdgcn_exp2f(((s0.y+s1.y)+(s2.y+s3.y))*LOG2E);
    v.z = __builtin_amdgcn_exp2f(((s0.z+s1.z)+(s2.z+s3.z))*LOG2E);
    v.w = __builtin_amdgcn_exp2f(((s0.w+s1.w)+(s2.w+s3.w))*LOG2E);
    if (is_q) {
        *(float4*)&qc[(size_t)(r0 + r)*128 + c4] = v;
    } else {
        int c    = (r0 & 1023) >> 6;    // 64-kv chunk
        int kvin = (r0 & 63) + r;       // kv within chunk
        *(float4*)&kct[((((size_t)(bb*16 + c))*32 + (c4 >> 2))*64 + kvin)*4] = v;
    }
}

// ---------------- Kernel 2: split-KV scores + softmax + PV partials --------
// grid (64 q-tiles, 4 b, 4 kv-splits) = 1024 blocks, 256 thr, LDS 12.3 KB,
// __launch_bounds__(256,8) -> 8 blocks/CU = 32 waves/CU (validated optimum)
// with HALF the kct+V L2 traffic of the 2q version: each kct/V load now
// feeds 4 q-rows. Block = (4 q, one 256-kv quarter). Wave w (of 4) owns
// chunk s*4+w (64 kv). Writes unnormalized O-partial + (m, l) per
// (split, row); combine_kernel merges 4 splits.
// Fully-masked splits (vl>0, s*256>=vl) write (m=-1e30, l=0) and exit;
// combine's w_s=0 annihilates their poison O. vl==0 runs the uniform path
// in all splits (all scores -1e6 -> e=1), matching the reference.
// Score math: sig = 1/(e^{2(q+k)}+1) = rcp(fma(t,t,1)), t = Eq*Ek, packed
// pairwise along h (v_pk_mul/fma_f32). PV: fp16 V pairs via v_dot2_f32_f16.
__global__ __launch_bounds__(256, 8) void attn_split_kernel(
    const float* __restrict__ qc, const float* __restrict__ kct,
    const unsigned int* __restrict__ vh, const int* __restrict__ valid_lens,
    const float* __restrict__ wv, float* __restrict__ pO, float* __restrict__ pml)
{
    __shared__ __align__(16) float4 e4_s[256];  // e for q0..q3 per local kv  4 KB
    __shared__ float4 po[4][2][64];             // PV wave partials (2 passes) 8 KB
    __shared__ float4 red_m[4], red_s[4];

    int tid  = threadIdx.x;
    int b    = blockIdx.y;
    int q0   = blockIdx.x * 4;
    int s    = blockIdx.z;              // kv quarter 0..3
    int w    = tid >> 6;                // wave 0..3
    int lane = tid & 63;
    int vl   = valid_lens[b];
    int row0 = b*256 + q0;

    if (s > 0 && vl > 0 && s*256 >= vl) {   // whole split masked: exit
        if (tid < 4) *(float2*)&pml[(size_t)(s*1024 + row0 + tid)*2] = make_float2(-1e30f, 0.f);
        return;
    }

    const float4* qr0 = (const float4*)(qc + (size_t)row0*128);
    const float4* qr1 = qr0 + 32;
    const float4* qr2 = qr0 + 64;
    const float4* qr3 = qr0 + 96;
    const float4* wv4 = (const float4*)wv;
    int chunk = s*4 + w;
    const float4* p0  = (const float4*)kct + ((size_t)(b*16 + chunk))*2048 + lane;

    const f32x2 one2 = {1.f, 1.f};
    f32x2 acc0 = {0.f,0.f}, acc1 = {0.f,0.f}, acc2 = {0.f,0.f}, acc3 = {0.f,0.f};

#define ROWOP(xq, accv) { \
        f32x2 t = ((const f32x2*)&(xq))[h] * kk; \
        f32x2 d = t*t + one2; \
        f32x2 rv = { __builtin_amdgcn_rcpf(d.x), __builtin_amdgcn_rcpf(d.y) }; \
        accv += ww * rv; }

    if (chunk*64 < vl) {                // wave-uniform skip of masked chunks
#pragma unroll 2
        for (int hb = 0; hb < 32; ++hb) {
            float4 k0 = p0[(size_t)hb*64];       // one dwordx4: 4 h of this kv
            float4 wvv = wv4[hb];
            float4 xa = qr0[hb], xb = qr1[hb], xc = qr2[hb], xd = qr3[hb];
            const f32x2* k2 = (const f32x2*)&k0;
            const f32x2* w2 = (const f32x2*)&wvv;
#pragma unroll
            for (int h = 0; h < 2; ++h) {
                f32x2 kk = k2[h];
                f32x2 ww = w2[h];
                ROWOP(xa, acc0);
                ROWOP(xb, acc1);
                ROWOP(xc, acc2);
                ROWOP(xd, acc3);
            }
        }
    }
#undef ROWOP
    float a0 = acc0.x + acc0.y;
    float a1 = acc1.x + acc1.y;
    float a2 = acc2.x + acc2.y;
    float a3 = acc3.x + acc3.y;

    // ---- mask + split-local softmax (4 rows) ----
    int lkv = w*64 + lane;              // local kv 0..255
    bool valid = (s*256 + lkv < vl);
    float s0 = valid ? -2.f*a0 : -1e6f;
    float s1 = valid ? -2.f*a1 : -1e6f;
    float s2 = valid ? -2.f*a2 : -1e6f;
    float s3 = valid ? -2.f*a3 : -1e6f;

    float m0 = s0, m1 = s1, m2 = s2, m3 = s3;
#pragma unroll
    for (int off = 32; off; off >>= 1) {
        m0 = fmaxf(m0, __shfl_xor(m0, off));
        m1 = fmaxf(m1, __shfl_xor(m1, off));
        m2 = fmaxf(m2, __shfl_xor(m2, off));
        m3 = fmaxf(m3, __shfl_xor(m3, off));
    }
    if (lane == 0) red_m[w] = make_float4(m0, m1, m2, m3);
    __syncthreads();
    {
        float4 mm = red_m[0];
#pragma unroll
        for (int ww2 = 1; ww2 < 4; ++ww2) {
            float4 t = red_m[ww2];
            mm.x = fmaxf(mm.x, t.x); mm.y = fmaxf(mm.y, t.y);
            mm.z = fmaxf(mm.z, t.z); mm.w = fmaxf(mm.w, t.w);
        }
        m0 = mm.x; m1 = mm.y; m2 = mm.z; m3 = mm.w;
    }

    float e0 = __builtin_amdgcn_exp2f((s0 - m0) * LOG2E);
    float e1 = __builtin_amdgcn_exp2f((s1 - m1) * LOG2E);
    float e2 = __builtin_amdgcn_exp2f((s2 - m2) * LOG2E);
    float e3 = __builtin_amdgcn_exp2f((s3 - m3) * LOG2E);
    e4_s[lkv] = make_float4(e0, e1, e2, e3);
    float l0 = e0, l1 = e1, l2 = e2, l3 = e3;
#pragma unroll
    for (int off = 32; off; off >>= 1) {
        l0 += __shfl_xor(l0, off);
        l1 += __shfl_xor(l1, off);
        l2 += __shfl_xor(l2, off);
        l3 += __shfl_xor(l3, off);
    }
    if (lane == 0) red_s[w] = make_float4(l0, l1, l2, l3);
    __syncthreads();

    // ---- PV over this split's valid kv pairs (e==0 beyond vl when vl>0) ----
    int local_end = (vl == 0) ? 256 : min(256, vl - s*256);
    int pair_end  = (local_end + 1) >> 1;       // <=128
    float4 ac0 = {0,0,0,0}, ac1 = {0,0,0,0}, ac2 = {0,0,0,0}, ac3 = {0,0,0,0};
    const uint4* VH = (const uint4*)vh + ((size_t)(b*512 + s*128))*64 + lane;
#pragma unroll 2
    for (int p = w; p < pair_end; p += 4) {
        uint4 vv = VH[(size_t)p*64];        // 4 cols x half2{r0,r1}, 16B/lane
        float4 E0 = e4_s[2*p], E1 = e4_s[2*p+1];
        fh2 eh0 = pk2f(__builtin_amdgcn_cvt_pkrtz(E0.x, E1.x));
        fh2 eh1 = pk2f(__builtin_amdgcn_cvt_pkrtz(E0.y, E1.y));
        fh2 eh2 = pk2f(__builtin_amdgcn_cvt_pkrtz(E0.z, E1.z));
        fh2 eh3 = pk2f(__builtin_amdgcn_cvt_pkrtz(E0.w, E1.w));
        fh2 v0 = bits2f(vv.x), v1 = bits2f(vv.y);
        fh2 v2 = bits2f(vv.z), v3 = bits2f(vv.w);
        ac0.x = __builtin_amdgcn_fdot2(eh0, v0, ac0.x, false);
        ac0.y = __builtin_amdgcn_fdot2(eh0, v1, ac0.y, false);
        ac0.z = __builtin_amdgcn_fdot2(eh0, v2, ac0.z, false);
        ac0.w = __builtin_amdgcn_fdot2(eh0, v3, ac0.w, false);
        ac1.x = __builtin_amdgcn_fdot2(eh1, v0, ac1.x, false);
        ac1.y = __builtin_amdgcn_fdot2(eh1, v1, ac1.y, false);
        ac1.z = __builtin_amdgcn_fdot2(eh1, v2, ac1.z, false);
        ac1.w = __builtin_amdgcn_fdot2(eh1, v3, ac1.w, false);
        ac2.x = __builtin_amdgcn_fdot2(eh2, v0, ac2.x, false);
        ac2.y = __builtin_amdgcn_fdot2(eh2, v1, ac2.y, false);
        ac2.z = __builtin_amdgcn_fdot2(eh2, v2, ac2.z, false);
        ac2.w = __builtin_amdgcn_fdot2(eh2, v3, ac2.w, false);
        ac3.x = __builtin_amdgcn_fdot2(eh3, v0, ac3.x, false);
        ac3.y = __builtin_amdgcn_fdot2(eh3, v1, ac3.y, false);
        ac3.z = __builtin_amdgcn_fdot2(eh3, v2, ac3.z, false);
        ac3.w = __builtin_amdgcn_fdot2(eh3, v3, ac3.w, false);
    }

    // per-row (m, l) to workspace
    if (tid < 4) {
        float lsum = 0.f;
#pragma unroll
        for (int ww2 = 0; ww2 < 4; ++ww2) {
            float4 t = red_s[ww2];
            lsum += (tid == 0) ? t.x : (tid == 1) ? t.y : (tid == 2) ? t.z : t.w;
        }
        float mm = (tid == 0) ? m0 : (tid == 1) ? m1 : (tid == 2) ? m2 : m3;
        *(float2*)&pml[(size_t)(s*1024 + row0 + tid)*2] = make_float2(mm, lsum);
    }

    // ---- combine 4 wave partials -> unnormalized O-partials (2 passes) ----
    int qq = tid >> 7;                  // 0..1
    int cp = tid & 127;                 // col pair
    const float2* pp2 = (const float2*)po;

    po[w][0][lane] = ac0;
    po[w][1][lane] = ac1;
    __syncthreads();
    {
        float2 r = make_float2(0.f, 0.f);
#pragma unroll
        for (int ww2 = 0; ww2 < 4; ++ww2) {
            float2 t = pp2[(ww2*2 + qq)*128 + cp];
            r.x += t.x; r.y += t.y;
        }
        *(float2*)&pO[(size_t)(s*1024 + row0 + qq)*256 + cp*2] = r;
    }
    __syncthreads();
    po[w][0][lane] = ac2;
    po[w][1][lane] = ac3;
    __syncthreads();
    {
        float2 r = make_float2(0.f, 0.f);
#pragma unroll
        for (int ww2 = 0; ww2 < 4; ++ww2) {
            float2 t = pp2[(ww2*2 + qq)*128 + cp];
            r.x += t.x; r.y += t.y;
        }
        *(float2*)&pO[(size_t)(s*1024 + row0 + 2 + qq)*256 + cp*2] = r;
    }
}

// ---------------- Kernel 3: merge the four KV-split partials ---------------
// 256 blocks x 256 thr; block = 4 rows, thread = (row, 4 v-cols).
__global__ __launch_bounds__(256) void combine_kernel(
    const float* __restrict__ pO, const float* __restrict__ pml,
    float* __restrict__ out)
{
    int tid  = threadIdx.x;
    int row  = blockIdx.x*4 + (tid >> 6);   // 0..1023
    int lane = tid & 63;
    float2 ml0 = *(const float2*)&pml[(size_t)row*2];
    float2 ml1 = *(const float2*)&pml[(size_t)(1024 + row)*2];
    float2 ml2 = *(const float2*)&pml[(size_t)(2048 + row)*2];
    float2 ml3 = *(const float2*)&pml[(size_t)(3072 + row)*2];
    float m  = fmaxf(fmaxf(ml0.x, ml1.x), fmaxf(ml2.x, ml3.x));
    float w0 = __builtin_amdgcn_exp2f((ml0.x - m) * LOG2E);
    float w1 = __builtin_amdgcn_exp2f((ml1.x - m) * LOG2E);
    float w2 = __builtin_amdgcn_exp2f((ml2.x - m) * LOG2E);
    float w3 = __builtin_amdgcn_exp2f((ml3.x - m) * LOG2E);
    float inv = 1.0f / (w0*ml0.y + w1*ml1.y + w2*ml2.y + w3*ml3.y);
    float4 o0 = ((const float4*)pO)[(size_t)row*64 + lane];
    float4 o1 = ((const float4*)pO)[(size_t)(1024 + row)*64 + lane];
    float4 o2 = ((const float4*)pO)[(size_t)(2048 + row)*64 + lane];
    float4 o3 = ((const float4*)pO)[(size_t)(3072 + row)*64 + lane];
    float4 o;
    o.x = (w0*o0.x + w1*o1.x + w2*o2.x + w3*o3.x) * inv;
    o.y = (w0*o0.y + w1*o1.y + w2*o2.y + w3*o3.y) * inv;
    o.z = (w0*o0.z + w1*o1.z + w2*o2.z + w3*o3.z) * inv;
    o.w = (w0*o0.w + w1*o1.w + w2*o2.w + w3*o3.w) * inv;
    ((float4*)out)[(size_t)row*64 + lane] = o;
}

extern "C" void kernel_launch(void* const* d_in, const int* in_sizes, int n_in,
                              void* d_out, int out_size, void* d_ws, size_t ws_size,
                              hipStream_t stream)
{
    const float* queries = (const float*)d_in[0];   // [4,256,128]
    const float* keys    = (const float*)d_in[1];   // [4,1024,128]
    const float* values  = (const float*)d_in[2];   // [4,1024,256]
    const int*   vlens   = (const int*)d_in[3];     // [4]
    const float* Wq      = (const float*)d_in[4];   // [128,128]
    const float* Wk      = (const float*)d_in[5];   // [128,128]
    const float* wv      = (const float*)d_in[6];   // [128]
    float* out = (float*)d_out;                     // [4,256,256]

    float* qc  = (float*)d_ws;                      // 4*256*128    = 512 KB
    float* kct = qc  + 4*256*128;                   // 4*16*32*64*4 = 2 MB (fp32)
    float* pO  = kct + 4*16*32*64*4;                // 4*1024*256   = 4 MB
    float* pml = pO  + 4*1024*256;                  // 4*1024*2     = 32 KB
    unsigned int* vh = (unsigned int*)(pml + 4*1024*2);  // 2048 pairs*256 h2 = 2 MB

    proj_kernel<<<1152, 256, 0, stream>>>(queries, keys, values, Wq, Wk, vlens, qc, kct, vh);
    attn_split_kernel<<<dim3(64, 4, 4), 256, 0, stream>>>(qc, kct, vh, vlens, wv, pO, pml);
    combine_kernel<<<256, 256, 0, stream>>>(pO, pml, out);
}

// Round 9
// 88.839 us; speedup vs baseline: 1.0452x; 1.0452x over previous
//
#include <hip/hip_runtime.h>

#define LOG2E   1.4426950408889634f

typedef _Float16 fh2 __attribute__((ext_vector_type(2)));   // fdot2 operand type
typedef __fp16   ph2 __attribute__((ext_vector_type(2)));   // cvt_pkrtz result type
typedef float    f32x2 __attribute__((ext_vector_type(2))); // v_pk_*_f32 operand
union h2u { fh2 f; ph2 p; unsigned int u; };
__device__ __forceinline__ unsigned int pk2bits(ph2 h) { h2u t; t.p = h; return t.u; }
__device__ __forceinline__ fh2 pk2f(ph2 h) { h2u t; t.p = h; return t.f; }
__device__ __forceinline__ fh2 bits2f(unsigned int u) { h2u t; t.u = u; return t.f; }

__device__ __forceinline__ unsigned int bf16rne(float x) {   // fp32 -> bf16 (RNE)
    unsigned int u = __float_as_uint(x);
    return (u + 0x7FFFu + ((u >> 16) & 1u)) >> 16;
}
__device__ __forceinline__ f32x2 bx2(unsigned int u) {       // bf16x2 -> f32x2
    f32x2 r;
    r.x = __uint_as_float(u << 16);
    r.y = __uint_as_float(u & 0xFFFF0000u);
    return r;
}

// ---------------- Kernel 1: fused projections (e^proj) + V fp16 pack -------
// 256 threads. blocks 0..127: qc rows (Eq = e^{q@Wq}, fp32). blocks 128..639:
// kct BF16 layout [b][c][h>>2][kv] of uint2 {h0h1, h2h3} holding
// Ek = e^{k@Wk}; K-blocks with all rows >= valid_len exit early (attn reads
// those rows only as benign poison in partially-masked chunks; scores are
// masked to -1e6). blocks 640..1151: pack V into fp16 kv-pairs:
// vh[b][p][c] = half2 {V[b][2p][c], V[b][2p+1][c]} for the dot2-based PV.
// Half-exponent trick: attn computes sig = 1/((Eq*Ek)^2 + 1); stored
// exponents have sigma~16.3 -> overflow needs 7.7 sigma (never), and product
// over/underflow saturates to the CORRECT sigmoid limit (rcp(inf)=0,
// rcp(0+1)=1). bf16 keeps fp32's exponent range; mantissa rel-err 2^-9 ->
// output delta ~0.01 << 0.0887 threshold (validated in R7, absmax 0.0156).
// KEY vs R7: attn loads stay 32 x dwordx2 per lane (same MLP depth as the
// fp32 champion) -- R7's 16 x dwordx4 halved MLP and regressed.
__global__ __launch_bounds__(256) void proj_kernel(
    const float* __restrict__ q_in, const float* __restrict__ k_in,
    const float* __restrict__ v_in,
    const float* __restrict__ Wq, const float* __restrict__ Wk,
    const int* __restrict__ valid_lens,
    float* __restrict__ qc, unsigned int* __restrict__ kct,
    unsigned int* __restrict__ vh)
{
    __shared__ __align__(16) float x_s[8][128];     // 4 KB
    __shared__ __align__(16) float ps[4][8][128];   // 16 KB
    int tid = threadIdx.x;
    int blk = blockIdx.x;

    if (blk >= 640) {                   // ---- V fp16 pair-pack branch ----
        int vb = blk - 640;             // 0..511
        int P  = vb*4 + (tid >> 6);     // global pair 0..2047
        int bb = P >> 9, p = P & 511;
        int lane = tid & 63;
        const float4* r0 = (const float4*)(v_in + ((size_t)(bb*1024 + 2*p))*256) + lane;
        float4 x0 = r0[0];
        float4 x1 = r0[64];             // next kv row (+256 floats)
        uint4 h;
        h.x = pk2bits(__builtin_amdgcn_cvt_pkrtz(x0.x, x1.x));
        h.y = pk2bits(__builtin_amdgcn_cvt_pkrtz(x0.y, x1.y));
        h.z = pk2bits(__builtin_amdgcn_cvt_pkrtz(x0.z, x1.z));
        h.w = pk2bits(__builtin_amdgcn_cvt_pkrtz(x0.w, x1.w));
        ((uint4*)vh)[(size_t)P*64 + lane] = h;
        return;
    }

    bool is_q = (blk < 128);
    int r0 = (is_q ? blk : blk - 128) * 8;
    int bb = r0 >> 10;
    if (!is_q) {
        int vl = valid_lens[bb];
        if ((r0 & 1023) >= vl) return;  // block-uniform: whole block exits
    }
    const float* X = (is_q ? q_in : k_in) + (size_t)r0 * 128;
    const float* W = is_q ? Wq : Wk;

    *(float4*)&x_s[tid >> 5][(tid & 31) * 4] = ((const float4*)X)[tid];
    __syncthreads();

    int hl = tid & 63;                  // column pair {hl, hl+64}
    int dq = tid >> 6;                  // d-quarter (wave-uniform)
    float a0[8] = {0,0,0,0,0,0,0,0};
    float a1[8] = {0,0,0,0,0,0,0,0};
#pragma unroll
    for (int i4 = 0; i4 < 8; ++i4) {
        int d = dq*32 + i4*4;
        float w00 = W[(d+0)*128 + hl], w01 = W[(d+0)*128 + hl + 64];
        float w10 = W[(d+1)*128 + hl], w11 = W[(d+1)*128 + hl + 64];
        float w20 = W[(d+2)*128 + hl], w21 = W[(d+2)*128 + hl + 64];
        float w30 = W[(d+3)*128 + hl], w31 = W[(d+3)*128 + hl + 64];
#pragma unroll
        for (int r = 0; r < 8; ++r) {
            float4 xv = *(const float4*)&x_s[r][d];   // wave-uniform broadcast
            a0[r] = fmaf(xv.x,w00, fmaf(xv.y,w10, fmaf(xv.z,w20, fmaf(xv.w,w30, a0[r]))));
            a1[r] = fmaf(xv.x,w01, fmaf(xv.y,w11, fmaf(xv.z,w21, fmaf(xv.w,w31, a1[r]))));
        }
    }
#pragma unroll
    for (int r = 0; r < 8; ++r) {
        ps[dq][r][hl]      = a0[r];
        ps[dq][r][hl + 64] = a1[r];
    }
    __syncthreads();

    int r  = tid >> 5;
    int c4 = (tid & 31) * 4;
    float4 s0 = *(const float4*)&ps[0][r][c4];
    float4 s1 = *(const float4*)&ps[1][r][c4];
    float4 s2 = *(const float4*)&ps[2][r][c4];
    float4 s3 = *(const float4*)&ps[3][r][c4];
    float4 v;
    v.x = __builtin_amdgcn_exp2f(((s0.x+s1.x)+(s2.x+s3.x))*LOG2E);
    v.y = __builtin_amdgcn_exp2f(((s0.y+s1.y)+(s2.y+s3.y))*LOG2E);
    v.z = __builtin_amdgcn_exp2f(((s0.z+s1.z)+(s2.z+s3.z))*LOG2E);
    v.w = __builtin_amdgcn_exp2f(((s0.w+s1.w)+(s2.w+s3.w))*LOG2E);
    if (is_q) {
        *(float4*)&qc[(size_t)(r0 + r)*128 + c4] = v;
    } else {
        int c    = (r0 & 1023) >> 6;    // 64-kv chunk
        int kvin = (r0 & 63) + r;       // kv within chunk
        unsigned int d0 = bf16rne(v.x) | (bf16rne(v.y) << 16);
        unsigned int d1 = bf16rne(v.z) | (bf16rne(v.w) << 16);
        size_t idx2 = (((size_t)(bb*16 + c))*32 + (c4 >> 2))*64 + kvin;   // uint2 units
        ((uint2*)kct)[idx2] = make_uint2(d0, d1);
    }
}

// ---------------- Kernel 2: split-KV scores + softmax + PV partials --------
// grid (128 q-tiles, 4 b, 2 kv-splits) = 1024 blocks, 512 thr -> 4 blocks/CU
// (32 waves/CU -- validated optimum; every structural rearrangement of this
// has regressed: R1 occupancy, R7 MLP, R8 spills).
// Block = (2 q, one 512-kv half). Wave w owns chunk s*8+w (64 kv). Writes
// unnormalized O-partial + (m, l) per (split, row); combine_kernel merges.
// Fully-masked s=1 blocks (0 < vl <= 512) write m=-1e30 and exit; combine's
// w1 = exp(m1-m) = 0 annihilates their poison l/O. vl==0 runs the uniform
// path in both splits (all scores -1e6 -> e=1), matching the reference.
// Score math: sig = 1/(e^{2(q+k)}+1) = rcp(fma(t,t,1)), t = Eq*Ek(bf16),
// packed pairwise along h (v_pk_mul/fma_f32). Loads: 32 x dwordx2 per lane
// (same count/stride pattern as the fp32 champion, half the bytes).
// PV: fp16 V pairs via v_dot2_f32_f16 (fp32 accum) -- 2 MACs/VALU slot.
__global__ __launch_bounds__(512, 8) void attn_split_kernel(
    const float* __restrict__ qc, const unsigned int* __restrict__ kct,
    const unsigned int* __restrict__ vh, const int* __restrict__ valid_lens,
    const float* __restrict__ wv, float* __restrict__ pO, float* __restrict__ pml)
{
    __shared__ __align__(16) float2 e2_s[512];  // (e_q0, e_q1) per local kv  4 KB
    __shared__ float4 po[8][2][64];             // PV wave partials          16 KB
    __shared__ float2 red_m[8], red_s[8];

    int tid  = threadIdx.x;
    int b    = blockIdx.y;
    int q0   = blockIdx.x * 2;
    int s    = blockIdx.z;              // kv half
    int w    = tid >> 6;                // wave 0..7
    int lane = tid & 63;
    int vl   = valid_lens[b];
    int row0 = b*256 + q0;

    if (s == 1 && vl > 0 && vl <= 512) {    // whole split masked: m=-1e30, exit
        if (tid < 2) pml[(size_t)(1024 + row0 + tid)*2] = -1e30f;
        return;
    }

    const float4* qa4 = (const float4*)(qc + (size_t)row0*128);
    const float4* qb4 = qa4 + 32;
    const float4* wv4 = (const float4*)wv;
    const uint2*  p0  = (const uint2*)kct + ((size_t)(b*16 + s*8 + w))*2048 + lane;

    const f32x2 one2 = {1.f, 1.f};
    f32x2 acc0 = {0.f, 0.f}, acc1 = {0.f, 0.f};

#define SCORE_PAIR(kp, qap, qbp, wvp) { \
        f32x2 t0 = (qap) * (kp); \
        f32x2 t1 = (qbp) * (kp); \
        f32x2 d0 = t0*t0 + one2; \
        f32x2 d1 = t1*t1 + one2; \
        f32x2 r0v = { __builtin_amdgcn_rcpf(d0.x), __builtin_amdgcn_rcpf(d0.y) }; \
        f32x2 r1v = { __builtin_amdgcn_rcpf(d1.x), __builtin_amdgcn_rcpf(d1.y) }; \
        acc0 += (wvp) * r0v; \
        acc1 += (wvp) * r1v; }

    if ((s*8 + w)*64 < vl) {            // wave-uniform skip of masked chunks
#pragma unroll 4
        for (int hb = 0; hb < 32; ++hb) {
            uint2 K = p0[(size_t)hb*64];         // one dwordx2: 4 h (bf16) of this kv
            float4 wvv = wv4[hb];
            float4 qa = qa4[hb], qb = qb4[hb];
            const f32x2* w2  = (const f32x2*)&wvv;
            const f32x2* qa2 = (const f32x2*)&qa;
            const f32x2* qb2 = (const f32x2*)&qb;
            SCORE_PAIR(bx2(K.x), qa2[0], qb2[0], w2[0]);
            SCORE_PAIR(bx2(K.y), qa2[1], qb2[1], w2[1]);
        }
    }
#undef SCORE_PAIR
    float a00 = acc0.x + acc0.y;
    float a10 = acc1.x + acc1.y;

    // ---- mask + split-local softmax ----
    int lkv = w*64 + lane;              // local kv 0..511
    bool valid = (s*512 + lkv < vl);
    float s00 = valid ? -2.f*a00 : -1e6f;
    float s10 = valid ? -2.f*a10 : -1e6f;

    float m0 = s00, m1 = s10;
#pragma unroll
    for (int off = 32; off; off >>= 1) {
        m0 = fmaxf(m0, __shfl_xor(m0, off));
        m1 = fmaxf(m1, __shfl_xor(m1, off));
    }
    if (lane == 0) red_m[w] = make_float2(m0, m1);
    __syncthreads();
    {
        float2 mm = red_m[0];
#pragma unroll
        for (int ww = 1; ww < 8; ++ww) {
            float2 t = red_m[ww];
            mm.x = fmaxf(mm.x, t.x); mm.y = fmaxf(mm.y, t.y);
        }
        m0 = mm.x; m1 = mm.y;
    }

    float e00 = __builtin_amdgcn_exp2f((s00 - m0) * LOG2E);
    float e10 = __builtin_amdgcn_exp2f((s10 - m1) * LOG2E);
    e2_s[lkv] = make_float2(e00, e10);
    float l0 = e00, l1 = e10;
#pragma unroll
    for (int off = 32; off; off >>= 1) {
        l0 += __shfl_xor(l0, off);
        l1 += __shfl_xor(l1, off);
    }
    if (lane == 0) red_s[w] = make_float2(l0, l1);
    __syncthreads();

    // ---- PV over this split's valid kv pairs (e==0 beyond vl when vl>0) ----
    // pair p covers kv {2p, 2p+1}; odd vl tails have e=0 on the dead lane.
    int local_end = (vl == 0) ? 512 : min(512, vl - s*512);
    int pair_end  = (local_end + 1) >> 1;
    float4 ac0 = {0,0,0,0}, ac1 = {0,0,0,0};
    const uint4* VH = (const uint4*)vh + ((size_t)b*512 + (size_t)s*256)*64 + lane;
#pragma unroll 2
    for (int p = w; p < pair_end; p += 8) {
        uint4 vv = VH[(size_t)p*64];        // 4 cols x half2{r0,r1}, 16B/lane
        float4 E = *(const float4*)&e2_s[2*p];  // (e0[2p],e1[2p],e0[2p+1],e1[2p+1])
        fh2 eh0 = pk2f(__builtin_amdgcn_cvt_pkrtz(E.x, E.z));
        fh2 eh1 = pk2f(__builtin_amdgcn_cvt_pkrtz(E.y, E.w));
        fh2 v0 = bits2f(vv.x), v1 = bits2f(vv.y);
        fh2 v2 = bits2f(vv.z), v3 = bits2f(vv.w);
        ac0.x = __builtin_amdgcn_fdot2(eh0, v0, ac0.x, false);
        ac0.y = __builtin_amdgcn_fdot2(eh0, v1, ac0.y, false);
        ac0.z = __builtin_amdgcn_fdot2(eh0, v2, ac0.z, false);
        ac0.w = __builtin_amdgcn_fdot2(eh0, v3, ac0.w, false);
        ac1.x = __builtin_amdgcn_fdot2(eh1, v0, ac1.x, false);
        ac1.y = __builtin_amdgcn_fdot2(eh1, v1, ac1.y, false);
        ac1.z = __builtin_amdgcn_fdot2(eh1, v2, ac1.z, false);
        ac1.w = __builtin_amdgcn_fdot2(eh1, v3, ac1.w, false);
    }
    po[w][0][lane] = ac0;
    po[w][1][lane] = ac1;

    // per-row (m, l) to workspace
    if (tid < 2) {
        float lsum = 0.f;
#pragma unroll
        for (int ww = 0; ww < 8; ++ww) {
            float2 t = red_s[ww];
            lsum += tid ? t.y : t.x;
        }
        float mm = tid ? m1 : m0;
        *(float2*)&pml[(size_t)(s*1024 + row0 + tid)*2] = make_float2(mm, lsum);
    }
    __syncthreads();

    // ---- combine 8 wave partials -> unnormalized O-partial ----
    int qq  = tid >> 8;                 // 0..1
    int col = tid & 255;
    const float* pp = (const float*)po;     // [(w*2+q)*256 + col]
    float r = 0.f;
#pragma unroll
    for (int ww = 0; ww < 8; ++ww) r += pp[(ww*2 + qq)*256 + col];
    pO[(size_t)(s*1024 + row0 + qq)*256 + col] = r;
}

// ---------------- Kernel 3: merge the two KV-split partials ----------------
// 256 blocks x 256 thr; block = 4 rows, thread = (row, 4 v-cols).
__global__ __launch_bounds__(256) void combine_kernel(
    const float* __restrict__ pO, const float* __restrict__ pml,
    float* __restrict__ out)
{
    int tid  = threadIdx.x;
    int row  = blockIdx.x*4 + (tid >> 6);   // 0..1023
    int lane = tid & 63;
    float2 ml0 = *(const float2*)&pml[(size_t)row*2];
    float2 ml1 = *(const float2*)&pml[(size_t)(1024 + row)*2];
    float m  = fmaxf(ml0.x, ml1.x);
    float w0 = __builtin_amdgcn_exp2f((ml0.x - m) * LOG2E);
    float w1 = __builtin_amdgcn_exp2f((ml1.x - m) * LOG2E);
    float inv = 1.0f / (w0*ml0.y + w1*ml1.y);
    float4 o0 = ((const float4*)pO)[(size_t)row*64 + lane];
    float4 o1 = ((const float4*)pO)[(size_t)(1024 + row)*64 + lane];
    float4 o;
    o.x = (w0*o0.x + w1*o1.x) * inv;
    o.y = (w0*o0.y + w1*o1.y) * inv;
    o.z = (w0*o0.z + w1*o1.z) * inv;
    o.w = (w0*o0.w + w1*o1.w) * inv;
    ((float4*)out)[(size_t)row*64 + lane] = o;
}

extern "C" void kernel_launch(void* const* d_in, const int* in_sizes, int n_in,
                              void* d_out, int out_size, void* d_ws, size_t ws_size,
                              hipStream_t stream)
{
    const float* queries = (const float*)d_in[0];   // [4,256,128]
    const float* keys    = (const float*)d_in[1];   // [4,1024,128]
    const float* values  = (const float*)d_in[2];   // [4,1024,256]
    const int*   vlens   = (const int*)d_in[3];     // [4]
    const float* Wq      = (const float*)d_in[4];   // [128,128]
    const float* Wk      = (const float*)d_in[5];   // [128,128]
    const float* wv      = (const float*)d_in[6];   // [128]
    float* out = (float*)d_out;                     // [4,256,256]

    float* qc = (float*)d_ws;                            // 4*256*128 f32   = 512 KB
    unsigned int* kct = (unsigned int*)(qc + 4*256*128); // 262144 dwords   = 1 MB (bf16x2)
    float* pO  = (float*)(kct + 262144);                 // 2*1024*256 f32  = 2 MB
    float* pml = pO + 2*1024*256;                        // 2*1024*2  f32   = 16 KB
    unsigned int* vh = (unsigned int*)(pml + 2*1024*2);  // 2048 pairs*256 half2 = 2 MB

    proj_kernel<<<1152, 256, 0, stream>>>(queries, keys, values, Wq, Wk, vlens, qc, kct, vh);
    attn_split_kernel<<<dim3(128, 4, 2), 512, 0, stream>>>(qc, kct, vh, vlens, wv, pO, pml);
    combine_kernel<<<256, 256, 0, stream>>>(pO, pml, out);
}

// Round 10
// 88.036 us; speedup vs baseline: 1.0547x; 1.0091x over previous
//
#include <hip/hip_runtime.h>

#define LOG2E   1.4426950408889634f

typedef _Float16 fh2 __attribute__((ext_vector_type(2)));   // fdot2 operand type
typedef __fp16   ph2 __attribute__((ext_vector_type(2)));   // cvt_pkrtz result type
typedef float    f32x2 __attribute__((ext_vector_type(2))); // v_pk_*_f32 operand
union h2u { fh2 f; ph2 p; unsigned int u; };
__device__ __forceinline__ unsigned int pk2bits(ph2 h) { h2u t; t.p = h; return t.u; }
__device__ __forceinline__ fh2 bits2f(unsigned int u) { h2u t; t.u = u; return t.f; }

// ---------------- Kernel 1: fused projections (e^proj) + V fp16 pack -------
// 256 threads. blocks 0..127: qc rows (Eq = e^{q@Wq}, fp32). blocks 128..639:
// kct fp32 layout [b][c][h>>2][kv][h&3] holding Ek = e^{k@Wk}; K-blocks with
// all rows >= valid_len exit early (attn reads those rows only as benign
// poison in partially-masked chunks; those scores are masked to -1e6).
// blocks 640..1151: pack V into fp16 kv-pairs: vh[b][p][c] = half2
// {V[b][2p][c], V[b][2p+1][c]} for the dot2-based PV.
// Half-exponent trick: attn computes sig = 1/((Eq*Ek)^2 + 1); stored
// exponents have sigma~16.3 -> overflow needs 7.7 sigma (never), and product
// over/underflow saturates to the CORRECT sigmoid limit (rcp(inf)=0,
// rcp(0+1)=1). No clamping needed.
// VALIDATED-FINAL STRUCTURE (session evidence): fp32 kct (bf16 variants
// null/regress: R7 -MLP, R9 null); 2q x 512thr x 2-split grid (4q variants
// regress: R1 occupancy, R8 spills); fp16-dot2 PV (R5 win).
__global__ __launch_bounds__(256) void proj_kernel(
    const float* __restrict__ q_in, const float* __restrict__ k_in,
    const float* __restrict__ v_in,
    const float* __restrict__ Wq, const float* __restrict__ Wk,
    const int* __restrict__ valid_lens,
    float* __restrict__ qc, float* __restrict__ kct,
    unsigned int* __restrict__ vh)
{
    __shared__ __align__(16) float x_s[8][128];     // 4 KB
    __shared__ __align__(16) float ps[4][8][128];   // 16 KB
    int tid = threadIdx.x;
    int blk = blockIdx.x;

    if (blk >= 640) {                   // ---- V fp16 pair-pack branch ----
        int vb = blk - 640;             // 0..511
        int P  = vb*4 + (tid >> 6);     // global pair 0..2047
        int bb = P >> 9, p = P & 511;
        int lane = tid & 63;
        const float4* r0 = (const float4*)(v_in + ((size_t)(bb*1024 + 2*p))*256) + lane;
        float4 x0 = r0[0];
        float4 x1 = r0[64];             // next kv row (+256 floats)
        uint4 h;
        h.x = pk2bits(__builtin_amdgcn_cvt_pkrtz(x0.x, x1.x));
        h.y = pk2bits(__builtin_amdgcn_cvt_pkrtz(x0.y, x1.y));
        h.z = pk2bits(__builtin_amdgcn_cvt_pkrtz(x0.z, x1.z));
        h.w = pk2bits(__builtin_amdgcn_cvt_pkrtz(x0.w, x1.w));
        ((uint4*)vh)[(size_t)P*64 + lane] = h;
        return;
    }

    bool is_q = (blk < 128);
    int r0 = (is_q ? blk : blk - 128) * 8;
    int bb = r0 >> 10;
    if (!is_q) {
        int vl = valid_lens[bb];
        if ((r0 & 1023) >= vl) return;  // block-uniform: whole block exits
    }
    const float* X = (is_q ? q_in : k_in) + (size_t)r0 * 128;
    const float* W = is_q ? Wq : Wk;

    *(float4*)&x_s[tid >> 5][(tid & 31) * 4] = ((const float4*)X)[tid];
    __syncthreads();

    int hl = tid & 63;                  // column pair {hl, hl+64}
    int dq = tid >> 6;                  // d-quarter (wave-uniform)
    float a0[8] = {0,0,0,0,0,0,0,0};
    float a1[8] = {0,0,0,0,0,0,0,0};
#pragma unroll
    for (int i4 = 0; i4 < 8; ++i4) {
        int d = dq*32 + i4*4;
        float w00 = W[(d+0)*128 + hl], w01 = W[(d+0)*128 + hl + 64];
        float w10 = W[(d+1)*128 + hl], w11 = W[(d+1)*128 + hl + 64];
        float w20 = W[(d+2)*128 + hl], w21 = W[(d+2)*128 + hl + 64];
        float w30 = W[(d+3)*128 + hl], w31 = W[(d+3)*128 + hl + 64];
#pragma unroll
        for (int r = 0; r < 8; ++r) {
            float4 xv = *(const float4*)&x_s[r][d];   // wave-uniform broadcast
            a0[r] = fmaf(xv.x,w00, fmaf(xv.y,w10, fmaf(xv.z,w20, fmaf(xv.w,w30, a0[r]))));
            a1[r] = fmaf(xv.x,w01, fmaf(xv.y,w11, fmaf(xv.z,w21, fmaf(xv.w,w31, a1[r]))));
        }
    }
#pragma unroll
    for (int r = 0; r < 8; ++r) {
        ps[dq][r][hl]      = a0[r];
        ps[dq][r][hl + 64] = a1[r];
    }
    __syncthreads();

    int r  = tid >> 5;
    int c4 = (tid & 31) * 4;
    float4 s0 = *(const float4*)&ps[0][r][c4];
    float4 s1 = *(const float4*)&ps[1][r][c4];
    float4 s2 = *(const float4*)&ps[2][r][c4];
    float4 s3 = *(const float4*)&ps[3][r][c4];
    float4 v;
    v.x = __builtin_amdgcn_exp2f(((s0.x+s1.x)+(s2.x+s3.x))*LOG2E);
    v.y = __builtin_amdgcn_exp2f(((s0.y+s1.y)+(s2.y+s3.y))*LOG2E);
    v.z = __builtin_amdgcn_exp2f(((s0.z+s1.z)+(s2.z+s3.z))*LOG2E);
    v.w = __builtin_amdgcn_exp2f(((s0.w+s1.w)+(s2.w+s3.w))*LOG2E);
    if (is_q) {
        *(float4*)&qc[(size_t)(r0 + r)*128 + c4] = v;
    } else {
        int c    = (r0 & 1023) >> 6;    // 64-kv chunk
        int kvin = (r0 & 63) + r;       // kv within chunk
        *(float4*)&kct[((((size_t)(bb*16 + c))*32 + (c4 >> 2))*64 + kvin)*4] = v;
    }
}

// ---------------- Kernel 2: split-KV scores + softmax + PV partials --------
// grid (128 q-tiles, 4 b, 2 kv-splits) = 1024 blocks, 512 thr -> 4 blocks/CU
// (32 waves/CU -- validated optimum). Block = (2 q, one 512-kv half). Wave w
// owns chunk s*8+w (64 kv). Writes unnormalized O-partial + (m, l) per
// (split, row); combine_kernel merges.
// Fully-masked s=1 blocks (0 < vl <= 512) write m=-1e30 and exit; combine's
// w1 = exp(m1-m) = 0 annihilates their poison l/O. vl==0 runs the uniform
// path in both splits (all scores -1e6 -> e=1), matching the reference.
// Score: sig = rcp(fma(t,t,1)), t = Eq*Ek, packed pairwise along h
// (v_pk_mul/fma_f32) -- trans-pipe-bound floor (R6/R9 nulls).
// PV: e stored in LDS as PREBUILT fp16 kv-pairs (written once per thread via
// ds_write_b16) so the inner loop is pure {8B broadcast read + 8 dot2} --
// drops 2 cvt_pkrtz + 8 LDS bytes per iteration vs converting at read time.
__global__ __launch_bounds__(512, 8) void attn_split_kernel(
    const float* __restrict__ qc, const float* __restrict__ kct,
    const unsigned int* __restrict__ vh, const int* __restrict__ valid_lens,
    const float* __restrict__ wv, float* __restrict__ pO, float* __restrict__ pml)
{
    __shared__ __align__(8) uint2 eh_s[256];    // [p]: {half2 e0-pair, half2 e1-pair} 2 KB
    __shared__ float4 po[8][2][64];             // PV wave partials                   16 KB
    __shared__ float2 red_m[8], red_s[8];

    int tid  = threadIdx.x;
    int b    = blockIdx.y;
    int q0   = blockIdx.x * 2;
    int s    = blockIdx.z;              // kv half
    int w    = tid >> 6;                // wave 0..7
    int lane = tid & 63;
    int vl   = valid_lens[b];
    int row0 = b*256 + q0;

    if (s == 1 && vl > 0 && vl <= 512) {    // whole split masked: m=-1e30, exit
        if (tid < 2) pml[(size_t)(1024 + row0 + tid)*2] = -1e30f;
        return;
    }

    const float4* qa4 = (const float4*)(qc + (size_t)row0*128);
    const float4* qb4 = qa4 + 32;
    const float4* wv4 = (const float4*)wv;
    const float4* p0  = (const float4*)kct + ((size_t)(b*16 + s*8 + w))*2048 + lane;

    const f32x2 one2 = {1.f, 1.f};
    f32x2 acc0 = {0.f, 0.f}, acc1 = {0.f, 0.f};
    if ((s*8 + w)*64 < vl) {            // wave-uniform skip of masked chunks
#pragma unroll 4
        for (int hb = 0; hb < 32; ++hb) {
            float4 wvv = wv4[hb];
            float4 qa = qa4[hb], qb = qb4[hb];
            float4 k0 = p0[(size_t)hb*64];       // one dwordx4: 4 h of this kv
            const f32x2* w2  = (const f32x2*)&wvv;
            const f32x2* qa2 = (const f32x2*)&qa;
            const f32x2* qb2 = (const f32x2*)&qb;
            const f32x2* k2  = (const f32x2*)&k0;
#pragma unroll
            for (int h = 0; h < 2; ++h) {
                f32x2 t0 = qa2[h] * k2[h];       // v_pk_mul_f32
                f32x2 t1 = qb2[h] * k2[h];
                f32x2 d0 = t0*t0 + one2;         // v_pk_fma_f32
                f32x2 d1 = t1*t1 + one2;
                f32x2 r0 = { __builtin_amdgcn_rcpf(d0.x), __builtin_amdgcn_rcpf(d0.y) };
                f32x2 r1 = { __builtin_amdgcn_rcpf(d1.x), __builtin_amdgcn_rcpf(d1.y) };
                acc0 += w2[h] * r0;              // v_pk_fma_f32
                acc1 += w2[h] * r1;
            }
        }
    }
    float a00 = acc0.x + acc0.y;
    float a10 = acc1.x + acc1.y;

    // ---- mask + split-local softmax ----
    int lkv = w*64 + lane;              // local kv 0..511
    bool valid = (s*512 + lkv < vl);
    float s00 = valid ? -2.f*a00 : -1e6f;
    float s10 = valid ? -2.f*a10 : -1e6f;

    float m0 = s00, m1 = s10;
#pragma unroll
    for (int off = 32; off; off >>= 1) {
        m0 = fmaxf(m0, __shfl_xor(m0, off));
        m1 = fmaxf(m1, __shfl_xor(m1, off));
    }
    if (lane == 0) red_m[w] = make_float2(m0, m1);
    __syncthreads();
    {
        float2 mm = red_m[0];
#pragma unroll
        for (int ww = 1; ww < 8; ++ww) {
            float2 t = red_m[ww];
            mm.x = fmaxf(mm.x, t.x); mm.y = fmaxf(mm.y, t.y);
        }
        m0 = mm.x; m1 = mm.y;
    }

    float e00 = __builtin_amdgcn_exp2f((s00 - m0) * LOG2E);
    float e10 = __builtin_amdgcn_exp2f((s10 - m1) * LOG2E);
    {   // store e as fp16 halves of the kv-pair layout: eh_s[p] =
        // {half2(e0[2p],e0[2p+1]), half2(e1[2p],e1[2p+1])}
        _Float16* ehh = (_Float16*)eh_s;
        int pidx = lkv >> 1, hi2 = lkv & 1;
        ehh[pidx*4 + hi2]     = (_Float16)e00;
        ehh[pidx*4 + 2 + hi2] = (_Float16)e10;
    }
    float l0 = e00, l1 = e10;
#pragma unroll
    for (int off = 32; off; off >>= 1) {
        l0 += __shfl_xor(l0, off);
        l1 += __shfl_xor(l1, off);
    }
    if (lane == 0) red_s[w] = make_float2(l0, l1);
    __syncthreads();

    // ---- PV over this split's valid kv pairs (e==0 beyond vl when vl>0) ----
    // pair p covers kv {2p, 2p+1}; odd vl tails have e=0 on the dead lane.
    int local_end = (vl == 0) ? 512 : min(512, vl - s*512);
    int pair_end  = (local_end + 1) >> 1;
    float4 ac0 = {0,0,0,0}, ac1 = {0,0,0,0};
    const uint4* VH = (const uint4*)vh + ((size_t)b*512 + (size_t)s*256)*64 + lane;
#pragma unroll 2
    for (int p = w; p < pair_end; p += 8) {
        uint4 vv = VH[(size_t)p*64];        // 4 cols x half2{r0,r1}, 16B/lane
        uint2 eu = eh_s[p];                 // 8B broadcast: prebuilt fp16 pairs
        fh2 eh0 = bits2f(eu.x);
        fh2 eh1 = bits2f(eu.y);
        fh2 v0 = bits2f(vv.x), v1 = bits2f(vv.y);
        fh2 v2 = bits2f(vv.z), v3 = bits2f(vv.w);
        ac0.x = __builtin_amdgcn_fdot2(eh0, v0, ac0.x, false);
        ac0.y = __builtin_amdgcn_fdot2(eh0, v1, ac0.y, false);
        ac0.z = __builtin_amdgcn_fdot2(eh0, v2, ac0.z, false);
        ac0.w = __builtin_amdgcn_fdot2(eh0, v3, ac0.w, false);
        ac1.x = __builtin_amdgcn_fdot2(eh1, v0, ac1.x, false);
        ac1.y = __builtin_amdgcn_fdot2(eh1, v1, ac1.y, false);
        ac1.z = __builtin_amdgcn_fdot2(eh1, v2, ac1.z, false);
        ac1.w = __builtin_amdgcn_fdot2(eh1, v3, ac1.w, false);
    }
    po[w][0][lane] = ac0;
    po[w][1][lane] = ac1;

    // per-row (m, l) to workspace
    if (tid < 2) {
        float lsum = 0.f;
#pragma unroll
        for (int ww = 0; ww < 8; ++ww) {
            float2 t = red_s[ww];
            lsum += tid ? t.y : t.x;
        }
        float mm = tid ? m1 : m0;
        *(float2*)&pml[(size_t)(s*1024 + row0 + tid)*2] = make_float2(mm, lsum);
    }
    __syncthreads();

    // ---- combine 8 wave partials -> unnormalized O-partial ----
    int qq  = tid >> 8;                 // 0..1
    int col = tid & 255;
    const float* pp = (const float*)po;     // [(w*2+q)*256 + col]
    float r = 0.f;
#pragma unroll
    for (int ww = 0; ww < 8; ++ww) r += pp[(ww*2 + qq)*256 + col];
    pO[(size_t)(s*1024 + row0 + qq)*256 + col] = r;
}

// ---------------- Kernel 3: merge the two KV-split partials ----------------
// 256 blocks x 256 thr; block = 4 rows, thread = (row, 4 v-cols).
__global__ __launch_bounds__(256) void combine_kernel(
    const float* __restrict__ pO, const float* __restrict__ pml,
    float* __restrict__ out)
{
    int tid  = threadIdx.x;
    int row  = blockIdx.x*4 + (tid >> 6);   // 0..1023
    int lane = tid & 63;
    float2 ml0 = *(const float2*)&pml[(size_t)row*2];
    float2 ml1 = *(const float2*)&pml[(size_t)(1024 + row)*2];
    float m  = fmaxf(ml0.x, ml1.x);
    float w0 = __builtin_amdgcn_exp2f((ml0.x - m) * LOG2E);
    float w1 = __builtin_amdgcn_exp2f((ml1.x - m) * LOG2E);
    float inv = 1.0f / (w0*ml0.y + w1*ml1.y);
    float4 o0 = ((const float4*)pO)[(size_t)row*64 + lane];
    float4 o1 = ((const float4*)pO)[(size_t)(1024 + row)*64 + lane];
    float4 o;
    o.x = (w0*o0.x + w1*o1.x) * inv;
    o.y = (w0*o0.y + w1*o1.y) * inv;
    o.z = (w0*o0.z + w1*o1.z) * inv;
    o.w = (w0*o0.w + w1*o1.w) * inv;
    ((float4*)out)[(size_t)row*64 + lane] = o;
}

extern "C" void kernel_launch(void* const* d_in, const int* in_sizes, int n_in,
                              void* d_out, int out_size, void* d_ws, size_t ws_size,
                              hipStream_t stream)
{
    const float* queries = (const float*)d_in[0];   // [4,256,128]
    const float* keys    = (const float*)d_in[1];   // [4,1024,128]
    const float* values  = (const float*)d_in[2];   // [4,1024,256]
    const int*   vlens   = (const int*)d_in[3];     // [4]
    const float* Wq      = (const float*)d_in[4];   // [128,128]
    const float* Wk      = (const float*)d_in[5];   // [128,128]
    const float* wv      = (const float*)d_in[6];   // [128]
    float* out = (float*)d_out;                     // [4,256,256]

    float* qc  = (float*)d_ws;                      // 4*256*128    = 512 KB
    float* kct = qc  + 4*256*128;                   // 4*16*32*64*4 = 2 MB (fp32)
    float* pO  = kct + 4*16*32*64*4;                // 2*1024*256   = 2 MB
    float* pml = pO  + 2*1024*256;                  // 2*1024*2     = 16 KB
    unsigned int* vh = (unsigned int*)(pml + 2*1024*2);  // 2048 pairs*256 half2 = 2 MB

    proj_kernel<<<1152, 256, 0, stream>>>(queries, keys, values, Wq, Wk, vlens, qc, kct, vh);
    attn_split_kernel<<<dim3(128, 4, 2), 512, 0, stream>>>(qc, kct, vh, vlens, wv, pO, pml);
    combine_kernel<<<256, 256, 0, stream>>>(pO, pml, out);
}